// Round 1
// baseline (439.034 us; speedup 1.0000x reference)
//
#include <hip/hip_runtime.h>

constexpr int kB = 8;
constexpr int kS = 512;
constexpr int kH = 768;

// tanh(x) = 1 - 2/(exp(2x)+1); argument passed is 2x.
// Safe at extremes: exp->inf => 1, exp->0 => -1.
__device__ __forceinline__ float tanh_from_2x(float two_x) {
    float e = __expf(two_x);
    return 1.0f - 2.0f * __builtin_amdgcn_rcpf(e + 1.0f);
}

__device__ __forceinline__ float waveMax(float v) {
#pragma unroll
    for (int off = 32; off > 0; off >>= 1) v = fmaxf(v, __shfl_xor(v, off, 64));
    return v;
}
__device__ __forceinline__ float waveSum(float v) {
#pragma unroll
    for (int off = 32; off > 0; off >>= 1) v += __shfl_xor(v, off, 64);
    return v;
}

// ---------------- K1: C[i,o] = sum_h A[i,h]*W[o,h] + bias[o]  (two weight sets via blockIdx.z)
// 64x64 tile, BK=16, 256 threads, 4x4 micro-tile. M=4096, N=768, K=768 (all divisible).
__global__ __launch_bounds__(256) void k1_dual_gemm(
    const float* __restrict__ A,
    const float* __restrict__ W0, const float* __restrict__ bias0,
    const float* __restrict__ W1, const float* __restrict__ bias1,
    float* __restrict__ out0, float* __restrict__ out1)
{
    const float* W    = blockIdx.z ? W1 : W0;
    const float* bias = blockIdx.z ? bias1 : bias0;
    float* out        = blockIdx.z ? out1 : out0;

    __shared__ float As[16][68];   // k-major (transposed) for vector reads
    __shared__ float Ws[16][68];

    const int m0 = blockIdx.y * 64;
    const int n0 = blockIdx.x * 64;
    const int tid = threadIdx.x;
    const int lrow = tid >> 2;            // 0..63
    const int lk4  = (tid & 3) << 2;      // 0,4,8,12
    const int is = tid >> 4;              // 0..15 (rows)
    const int js = tid & 15;              // 0..15 (cols)

    const float* arow = A + (size_t)(m0 + lrow) * kH + lk4;
    const float* wrow = W + (size_t)(n0 + lrow) * kH + lk4;

    float acc[4][4] = {};

    for (int h0 = 0; h0 < kH; h0 += 16) {
        float4 av = *(const float4*)(arow + h0);
        float4 wv = *(const float4*)(wrow + h0);
        __syncthreads();
        As[lk4 + 0][lrow] = av.x;
        As[lk4 + 1][lrow] = av.y;
        As[lk4 + 2][lrow] = av.z;
        As[lk4 + 3][lrow] = av.w;
        Ws[lk4 + 0][lrow] = wv.x;
        Ws[lk4 + 1][lrow] = wv.y;
        Ws[lk4 + 2][lrow] = wv.z;
        Ws[lk4 + 3][lrow] = wv.w;
        __syncthreads();
#pragma unroll
        for (int kk = 0; kk < 16; ++kk) {
            const float* ap = &As[kk][is << 2];
            const float* bp = &Ws[kk][js << 2];
            float aa[4], bb[4];
#pragma unroll
            for (int c = 0; c < 4; ++c) { aa[c] = ap[c]; bb[c] = bp[c]; }
#pragma unroll
            for (int i = 0; i < 4; ++i)
#pragma unroll
                for (int j = 0; j < 4; ++j)
                    acc[i][j] = fmaf(aa[i], bb[j], acc[i][j]);
        }
    }

    float4 bv = *(const float4*)(bias + n0 + (js << 2));
#pragma unroll
    for (int i = 0; i < 4; ++i) {
        int row = m0 + (is << 2) + i;
        float4 o;
        o.x = acc[i][0] + bv.x;
        o.y = acc[i][1] + bv.y;
        o.z = acc[i][2] + bv.z;
        o.w = acc[i][3] + bv.w;
        *(float4*)(out + (size_t)row * kH + n0 + (js << 2)) = o;
    }
}

// ---------------- K2: scores[b, j, k] = sum_h tanh(Wq[b,start+j,h] + Uk[b,k,h]) * va[h]
// Only tiles with j0 < S-start && k0 < start do work. 32x32 tile, 2x2 micro, BH=16.
__global__ __launch_bounds__(256) void k2_scores(
    const float* __restrict__ Wq, const float* __restrict__ Uk,
    const float* __restrict__ va, const int* __restrict__ mask,
    float* __restrict__ scores)
{
    const int b = blockIdx.z;
    const int start = mask[2 * b];
    const int jmax = kS - start;
    const int j0 = blockIdx.y * 32;
    const int k0 = blockIdx.x * 32;
    if (j0 >= jmax || k0 >= start) return;

    __shared__ float Qs[16][36];   // holds 2*Wq (fold the *2 of tanh arg)
    __shared__ float Ks[16][36];   // holds 2*Uk
    __shared__ float vas[kH];

    const int tid = threadIdx.x;
    for (int i = tid; i < kH; i += 256) vas[i] = va[i];

    const int lrow = tid >> 3;           // 0..31
    const int lh2  = (tid & 7) << 1;     // 0,2,...,14
    const int is = tid >> 4;             // 0..15 (j pairs)
    const int js = tid & 15;             // 0..15 (k pairs)

    int tq = start + j0 + lrow;
    if (tq > kS - 1) tq = kS - 1;        // clamped rows produce garbage scores, never read
    const float* qrow = Wq + ((size_t)b * kS + tq) * kH + lh2;
    const float* krow = Uk + ((size_t)b * kS + k0 + lrow) * kH + lh2;

    float acc[2][2] = {};

    for (int h0 = 0; h0 < kH; h0 += 16) {
        float2 qv = *(const float2*)(qrow + h0);
        float2 kv = *(const float2*)(krow + h0);
        __syncthreads();
        Qs[lh2 + 0][lrow] = qv.x + qv.x;
        Qs[lh2 + 1][lrow] = qv.y + qv.y;
        Ks[lh2 + 0][lrow] = kv.x + kv.x;
        Ks[lh2 + 1][lrow] = kv.y + kv.y;
        __syncthreads();
#pragma unroll
        for (int kk = 0; kk < 16; ++kk) {
            float vah = vas[h0 + kk];
            float qa0 = Qs[kk][(is << 1) + 0];
            float qa1 = Qs[kk][(is << 1) + 1];
            float ka0 = Ks[kk][(js << 1) + 0];
            float ka1 = Ks[kk][(js << 1) + 1];
            acc[0][0] = fmaf(tanh_from_2x(qa0 + ka0), vah, acc[0][0]);
            acc[0][1] = fmaf(tanh_from_2x(qa0 + ka1), vah, acc[0][1]);
            acc[1][0] = fmaf(tanh_from_2x(qa1 + ka0), vah, acc[1][0]);
            acc[1][1] = fmaf(tanh_from_2x(qa1 + ka1), vah, acc[1][1]);
        }
    }

#pragma unroll
    for (int i = 0; i < 2; ++i) {
        int jrow = j0 + (is << 1) + i;
        float2 o = {acc[i][0], acc[i][1]};
        *(float2*)(scores + ((size_t)b * kS + jrow) * kS + k0 + (js << 1)) = o;
    }
}

// ---------------- K3: in-place row softmax over k < start; exact zeros elsewhere.
__global__ __launch_bounds__(256) void k3_softmax(
    float* __restrict__ attn, const int* __restrict__ mask)
{
    const int bx = blockIdx.x;
    const int b = bx >> 9;
    const int j = bx & (kS - 1);
    const int start = mask[2 * b];
    float* row = attn + ((size_t)b * kS + j) * kS;
    const int tid = threadIdx.x;

    if (j >= kS - start) {              // q_mask zeroes the whole row
        row[tid] = 0.0f;
        row[tid + 256] = 0.0f;
        return;
    }

    float v0 = (tid < start) ? row[tid] : -1e30f;
    float v1 = (tid + 256 < start) ? row[tid + 256] : -1e30f;

    __shared__ float red[4];
    const int wid = tid >> 6;

    float m = waveMax(fmaxf(v0, v1));
    if ((tid & 63) == 0) red[wid] = m;
    __syncthreads();
    m = fmaxf(fmaxf(red[0], red[1]), fmaxf(red[2], red[3]));
    __syncthreads();

    float e0 = (tid < start) ? __expf(v0 - m) : 0.0f;
    float e1 = (tid + 256 < start) ? __expf(v1 - m) : 0.0f;
    float s = waveSum(e0 + e1);
    if ((tid & 63) == 0) red[wid] = s;
    __syncthreads();
    s = red[0] + red[1] + red[2] + red[3];

    float inv = __builtin_amdgcn_rcpf(s);
    row[tid] = e0 * inv;
    row[tid + 256] = e1 * inv;
}

// ---------------- K4: ctx[b,j,h] = sum_k attn[b,j,k] * outputs[b,k,h], K bounded by start.
// 64x64 tile, BK=16, 256 threads, 4x4 micro.
__global__ __launch_bounds__(256) void k4_context(
    const float* __restrict__ attn, const float* __restrict__ outs,
    const int* __restrict__ mask, float* __restrict__ ctx)
{
    const int b = blockIdx.z;
    const int start = mask[2 * b];
    const int kmax = (start + 15) & ~15;   // attn is exactly 0 for k>=start, safe to round up
    const int m0 = blockIdx.y * 64;
    const int n0 = blockIdx.x * 64;

    __shared__ float As[16][68];   // k-major attn tile
    __shared__ float Bs[16][68];   // row-major outputs tile

    const int tid = threadIdx.x;
    const int lrow = tid >> 2;            // 0..63
    const int lk4  = (tid & 3) << 2;
    const int brow = tid >> 4;            // 0..15 (k)
    const int bh4  = (tid & 15) << 2;     // 0..60 (h)
    const int is = tid >> 4;
    const int js = tid & 15;

    const float* arow = attn + ((size_t)b * kS + m0 + lrow) * kS + lk4;
    const float* bbase = outs + (size_t)b * kS * kH + n0 + bh4;

    float acc[4][4] = {};

    for (int k0 = 0; k0 < kmax; k0 += 16) {
        float4 av = *(const float4*)(arow + k0);
        float4 bv = *(const float4*)(bbase + (size_t)(k0 + brow) * kH);
        __syncthreads();
        As[lk4 + 0][lrow] = av.x;
        As[lk4 + 1][lrow] = av.y;
        As[lk4 + 2][lrow] = av.z;
        As[lk4 + 3][lrow] = av.w;
        *(float4*)&Bs[brow][bh4] = bv;
        __syncthreads();
#pragma unroll
        for (int kk = 0; kk < 16; ++kk) {
            const float* ap = &As[kk][is << 2];
            const float* bp = &Bs[kk][js << 2];
            float aa[4], bb[4];
#pragma unroll
            for (int c = 0; c < 4; ++c) { aa[c] = ap[c]; bb[c] = bp[c]; }
#pragma unroll
            for (int i = 0; i < 4; ++i)
#pragma unroll
                for (int j = 0; j < 4; ++j)
                    acc[i][j] = fmaf(aa[i], bb[j], acc[i][j]);
        }
    }

#pragma unroll
    for (int i = 0; i < 4; ++i) {
        int row = m0 + (is << 2) + i;
        float4 o = {acc[i][0], acc[i][1], acc[i][2], acc[i][3]};
        *(float4*)(ctx + ((size_t)b * kS + row) * kH + n0 + (js << 2)) = o;
    }
}

extern "C" void kernel_launch(void* const* d_in, const int* in_sizes, int n_in,
                              void* d_out, int out_size, void* d_ws, size_t ws_size,
                              hipStream_t stream)
{
    const float* outputs = (const float*)d_in[0];
    const int*   mask    = (const int*)d_in[1];
    const float* Wa_w    = (const float*)d_in[2];
    const float* Wa_b    = (const float*)d_in[3];
    const float* Ua_w    = (const float*)d_in[4];
    const float* Ua_b    = (const float*)d_in[5];
    const float* Va_w    = (const float*)d_in[6];
    // Va_b shifts every valid score equally -> cancels in softmax -> unused.

    float* attn = (float*)d_out;                          // (B,S,S) — also scores scratch
    float* ctx  = attn + (size_t)kB * kS * kS;            // (B,S,H)

    float* Wq = (float*)d_ws;                             // (B*S, H) in workspace
    float* Uk = ctx;                                      // (B*S, H) — ctx region is free until K4

    // K1: Wq and Uk
    k1_dual_gemm<<<dim3(kH / 64, (kB * kS) / 64, 2), 256, 0, stream>>>(
        outputs, Wa_w, Wa_b, Ua_w, Ua_b, Wq, Uk);

    // K2: scores into the attentions region
    k2_scores<<<dim3(kS / 32, kS / 32, kB), 256, 0, stream>>>(Wq, Uk, Va_w, mask, attn);

    // K3: softmax + exact-zero masking (covers every element of attn region)
    k3_softmax<<<dim3(kB * kS), 256, 0, stream>>>(attn, mask);

    // K4: contexts (covers every element of ctx region, overwriting Uk scratch)
    k4_context<<<dim3(kH / 64, kS / 64, kB), 256, 0, stream>>>(attn, outputs, mask, ctx);
}

// Round 2
// 274.209 us; speedup vs baseline: 1.6011x; 1.6011x over previous
//
#include <hip/hip_runtime.h>

constexpr int kB = 8;
constexpr int kS = 512;
constexpr int kH = 768;

// tanh(x) = 1 - 2/(exp(2x)+1); argument passed is 2x.
__device__ __forceinline__ float tanh_from_2x(float two_x) {
    float e = __expf(two_x);
    return 1.0f - 2.0f * __builtin_amdgcn_rcpf(e + 1.0f);
}

__device__ __forceinline__ float waveMax(float v) {
#pragma unroll
    for (int off = 32; off > 0; off >>= 1) v = fmaxf(v, __shfl_xor(v, off, 64));
    return v;
}
__device__ __forceinline__ float waveSum(float v) {
#pragma unroll
    for (int off = 32; off > 0; off >>= 1) v += __shfl_xor(v, off, 64);
    return v;
}

// ---------------- K1: C[i,o] = sum_h A[i,h]*W[o,h] + bias[o]  (two weight sets via blockIdx.z)
__global__ __launch_bounds__(256) void k1_dual_gemm(
    const float* __restrict__ A,
    const float* __restrict__ W0, const float* __restrict__ bias0,
    const float* __restrict__ W1, const float* __restrict__ bias1,
    float* __restrict__ out0, float* __restrict__ out1)
{
    const float* W    = blockIdx.z ? W1 : W0;
    const float* bias = blockIdx.z ? bias1 : bias0;
    float* out        = blockIdx.z ? out1 : out0;

    __shared__ float As[16][68];
    __shared__ float Ws[16][68];

    const int m0 = blockIdx.y * 64;
    const int n0 = blockIdx.x * 64;
    const int tid = threadIdx.x;
    const int lrow = tid >> 2;
    const int lk4  = (tid & 3) << 2;
    const int is = tid >> 4;
    const int js = tid & 15;

    const float* arow = A + (size_t)(m0 + lrow) * kH + lk4;
    const float* wrow = W + (size_t)(n0 + lrow) * kH + lk4;

    float acc[4][4] = {};

    for (int h0 = 0; h0 < kH; h0 += 16) {
        float4 av = *(const float4*)(arow + h0);
        float4 wv = *(const float4*)(wrow + h0);
        __syncthreads();
        As[lk4 + 0][lrow] = av.x;
        As[lk4 + 1][lrow] = av.y;
        As[lk4 + 2][lrow] = av.z;
        As[lk4 + 3][lrow] = av.w;
        Ws[lk4 + 0][lrow] = wv.x;
        Ws[lk4 + 1][lrow] = wv.y;
        Ws[lk4 + 2][lrow] = wv.z;
        Ws[lk4 + 3][lrow] = wv.w;
        __syncthreads();
#pragma unroll
        for (int kk = 0; kk < 16; ++kk) {
            const float* ap = &As[kk][is << 2];
            const float* bp = &Ws[kk][js << 2];
            float aa[4], bb[4];
#pragma unroll
            for (int c = 0; c < 4; ++c) { aa[c] = ap[c]; bb[c] = bp[c]; }
#pragma unroll
            for (int i = 0; i < 4; ++i)
#pragma unroll
                for (int j = 0; j < 4; ++j)
                    acc[i][j] = fmaf(aa[i], bb[j], acc[i][j]);
        }
    }

    float4 bv = *(const float4*)(bias + n0 + (js << 2));
#pragma unroll
    for (int i = 0; i < 4; ++i) {
        int row = m0 + (is << 2) + i;
        float4 o;
        o.x = acc[i][0] + bv.x;
        o.y = acc[i][1] + bv.y;
        o.z = acc[i][2] + bv.z;
        o.w = acc[i][3] + bv.w;
        *(float4*)(out + (size_t)row * kH + n0 + (js << 2)) = o;
    }
}

// ---------------- K2a: build compacted work-list of valid 32x32 (j,k) tiles x H-chunks.
// wl[0] = ntiles; wl[1..] = (b<<20)|(jt<<12)|(kt<<4)|chunk
__global__ void k2a_worklist(const int* __restrict__ mask, int* __restrict__ wl, int nchunks)
{
    __shared__ int ne[kB], off[kB];
    const int tid = threadIdx.x;
    if (tid < kB) {
        int start = mask[2 * tid];
        int nj = (kS - start + 31) >> 5;
        int nk = (start + 31) >> 5;
        ne[tid] = nj * nk * nchunks;
    }
    __syncthreads();
    if (tid == 0) {
        int s = 0;
        for (int b = 0; b < kB; ++b) { off[b] = s; s += ne[b]; }
        wl[0] = s;
    }
    __syncthreads();
    for (int b = 0; b < kB; ++b) {
        int start = mask[2 * b];
        int nk = (start + 31) >> 5;
        int nkc = nk * nchunks;
        int n = ne[b];
        int base = off[b];
        for (int t = tid; t < n; t += blockDim.x) {
            int jt = t / nkc;
            int r = t - jt * nkc;
            int kt = r / nchunks;
            int c = r - kt * nchunks;
            wl[1 + base + t] = (b << 20) | (jt << 12) | (kt << 4) | c;
        }
    }
}

// ---------------- K2: scores[b, j, k] = sum_{h in chunk} tanh(Wq[b,start+j,h] + Uk[b,k,h]) * va[h]
// Persistent blocks grid-stride over the compacted work-list.
__global__ __launch_bounds__(256) void k2_scores(
    const float* __restrict__ Wq, const float* __restrict__ Uk,
    const float* __restrict__ va, const int* __restrict__ mask,
    const int* __restrict__ wl,
    float* __restrict__ part0, float* __restrict__ part1, int nchunks)
{
    __shared__ float Qs[16][36];   // holds 2*Wq (fold the *2 of tanh arg)
    __shared__ float Ks[16][36];   // holds 2*Uk
    __shared__ float vas[kH];

    const int tid = threadIdx.x;
    for (int i = tid; i < kH; i += 256) vas[i] = va[i];

    const int ntiles = wl[0];
    const int HC = kH / nchunks;

    const int lrow = tid >> 3;           // 0..31
    const int lh2  = (tid & 7) << 1;     // 0,2,...,14
    const int is = tid >> 4;             // 0..15 (j pairs)
    const int js = tid & 15;             // 0..15 (k pairs)

    for (int w = blockIdx.x; w < ntiles; w += gridDim.x) {
        const int e = wl[1 + w];
        const int b  = e >> 20;
        const int jt = (e >> 12) & 255;
        const int kt = (e >> 4) & 255;
        const int c  = e & 15;
        const int start = mask[2 * b];
        const int j0 = jt << 5;
        const int k0 = kt << 5;
        const int hbase = c * HC;

        int tq = start + j0 + lrow;
        if (tq > kS - 1) tq = kS - 1;    // clamped rows produce garbage, zeroed by K3
        const float* qrow = Wq + ((size_t)b * kS + tq) * kH + lh2;
        const float* krow = Uk + ((size_t)b * kS + k0 + lrow) * kH + lh2;

        float acc[2][2] = {};

        for (int h0 = hbase; h0 < hbase + HC; h0 += 16) {
            float2 qv = *(const float2*)(qrow + h0);
            float2 kv = *(const float2*)(krow + h0);
            __syncthreads();
            Qs[lh2 + 0][lrow] = qv.x + qv.x;
            Qs[lh2 + 1][lrow] = qv.y + qv.y;
            Ks[lh2 + 0][lrow] = kv.x + kv.x;
            Ks[lh2 + 1][lrow] = kv.y + kv.y;
            __syncthreads();
#pragma unroll
            for (int kk = 0; kk < 16; ++kk) {
                float vah = vas[h0 + kk];
                float qa0 = Qs[kk][(is << 1) + 0];
                float qa1 = Qs[kk][(is << 1) + 1];
                float ka0 = Ks[kk][(js << 1) + 0];
                float ka1 = Ks[kk][(js << 1) + 1];
                acc[0][0] = fmaf(tanh_from_2x(qa0 + ka0), vah, acc[0][0]);
                acc[0][1] = fmaf(tanh_from_2x(qa0 + ka1), vah, acc[0][1]);
                acc[1][0] = fmaf(tanh_from_2x(qa1 + ka0), vah, acc[1][0]);
                acc[1][1] = fmaf(tanh_from_2x(qa1 + ka1), vah, acc[1][1]);
            }
        }

        float* out = (c == 0) ? part0 : part1;
#pragma unroll
        for (int i = 0; i < 2; ++i) {
            int jrow = j0 + (is << 1) + i;
            float2 o = {acc[i][0], acc[i][1]};
            *(float2*)(out + ((size_t)b * kS + jrow) * kS + k0 + (js << 1)) = o;
        }
    }
}

// ---------------- K3: row softmax over k < start (summing H-chunk partials); exact zeros elsewhere.
__global__ __launch_bounds__(256) void k3_softmax(
    float* __restrict__ attn, const float* __restrict__ part1,
    const int* __restrict__ mask, int nchunks)
{
    const int bx = blockIdx.x;
    const int b = bx >> 9;
    const int j = bx & (kS - 1);
    const int start = mask[2 * b];
    float* row = attn + ((size_t)b * kS + j) * kS;
    const int tid = threadIdx.x;

    if (j >= kS - start) {
        row[tid] = 0.0f;
        row[tid + 256] = 0.0f;
        return;
    }

    const float* p1row = part1 + ((size_t)b * kS + j) * kS;
    float v0 = -1e30f, v1 = -1e30f;
    if (nchunks == 2) {
        if (tid < start)       v0 = row[tid] + p1row[tid];
        if (tid + 256 < start) v1 = row[tid + 256] + p1row[tid + 256];
    } else {
        if (tid < start)       v0 = row[tid];
        if (tid + 256 < start) v1 = row[tid + 256];
    }

    __shared__ float red[4];
    const int wid = tid >> 6;

    float m = waveMax(fmaxf(v0, v1));
    if ((tid & 63) == 0) red[wid] = m;
    __syncthreads();
    m = fmaxf(fmaxf(red[0], red[1]), fmaxf(red[2], red[3]));
    __syncthreads();

    float e0 = (tid < start) ? __expf(v0 - m) : 0.0f;
    float e1 = (tid + 256 < start) ? __expf(v1 - m) : 0.0f;
    float s = waveSum(e0 + e1);
    if ((tid & 63) == 0) red[wid] = s;
    __syncthreads();
    s = red[0] + red[1] + red[2] + red[3];

    float inv = __builtin_amdgcn_rcpf(s);
    row[tid] = e0 * inv;
    row[tid + 256] = e1 * inv;
}

// ---------------- K4: ctx[b,j,h] = sum_k attn[b,j,k] * outputs[b,k,h], K bounded by start.
__global__ __launch_bounds__(256) void k4_context(
    const float* __restrict__ attn, const float* __restrict__ outs,
    const int* __restrict__ mask, float* __restrict__ ctx)
{
    const int b = blockIdx.z;
    const int start = mask[2 * b];
    const int kmax = (start + 15) & ~15;
    const int m0 = blockIdx.y * 64;
    const int n0 = blockIdx.x * 64;

    __shared__ float As[16][68];
    __shared__ float Bs[16][68];

    const int tid = threadIdx.x;
    const int lrow = tid >> 2;
    const int lk4  = (tid & 3) << 2;
    const int brow = tid >> 4;
    const int bh4  = (tid & 15) << 2;
    const int is = tid >> 4;
    const int js = tid & 15;

    const float* arow = attn + ((size_t)b * kS + m0 + lrow) * kS + lk4;
    const float* bbase = outs + (size_t)b * kS * kH + n0 + bh4;

    float acc[4][4] = {};

    for (int k0 = 0; k0 < kmax; k0 += 16) {
        float4 av = *(const float4*)(arow + k0);
        float4 bv = *(const float4*)(bbase + (size_t)(k0 + brow) * kH);
        __syncthreads();
        As[lk4 + 0][lrow] = av.x;
        As[lk4 + 1][lrow] = av.y;
        As[lk4 + 2][lrow] = av.z;
        As[lk4 + 3][lrow] = av.w;
        *(float4*)&Bs[brow][bh4] = bv;
        __syncthreads();
#pragma unroll
        for (int kk = 0; kk < 16; ++kk) {
            const float* ap = &As[kk][is << 2];
            const float* bp = &Bs[kk][js << 2];
            float aa[4], bb[4];
#pragma unroll
            for (int c = 0; c < 4; ++c) { aa[c] = ap[c]; bb[c] = bp[c]; }
#pragma unroll
            for (int i = 0; i < 4; ++i)
#pragma unroll
                for (int j = 0; j < 4; ++j)
                    acc[i][j] = fmaf(aa[i], bb[j], acc[i][j]);
        }
    }

#pragma unroll
    for (int i = 0; i < 4; ++i) {
        int row = m0 + (is << 2) + i;
        float4 o = {acc[i][0], acc[i][1], acc[i][2], acc[i][3]};
        *(float4*)(ctx + ((size_t)b * kS + row) * kH + n0 + (js << 2)) = o;
    }
}

extern "C" void kernel_launch(void* const* d_in, const int* in_sizes, int n_in,
                              void* d_out, int out_size, void* d_ws, size_t ws_size,
                              hipStream_t stream)
{
    const float* outputs = (const float*)d_in[0];
    const int*   mask    = (const int*)d_in[1];
    const float* Wa_w    = (const float*)d_in[2];
    const float* Wa_b    = (const float*)d_in[3];
    const float* Ua_w    = (const float*)d_in[4];
    const float* Ua_b    = (const float*)d_in[5];
    const float* Va_w    = (const float*)d_in[6];
    // Va_b cancels in softmax -> unused.

    float* attn = (float*)d_out;                          // (B,S,S) — also scores partial 0
    float* ctx  = attn + (size_t)kB * kS * kS;            // (B,S,H)

    // Workspace layout: [worklist 16KB][Wq 12.58MB][part1 8.39MB (optional)]
    constexpr size_t kWlBytes   = 16 * 1024;
    constexpr size_t kWqBytes   = (size_t)kB * kS * kH * sizeof(float);
    constexpr size_t kPartBytes = (size_t)kB * kS * kS * sizeof(float);

    int* wl     = (int*)d_ws;
    float* Wq   = (float*)((char*)d_ws + kWlBytes);
    float* Uk   = ctx;                                    // ctx region free until K4
    const int nchunks = (ws_size >= kWlBytes + kWqBytes + kPartBytes) ? 2 : 1;
    float* part1 = (nchunks == 2) ? (float*)((char*)d_ws + kWlBytes + kWqBytes) : attn;

    // K1: Wq and Uk
    k1_dual_gemm<<<dim3(kH / 64, (kB * kS) / 64, 2), 256, 0, stream>>>(
        outputs, Wa_w, Wa_b, Ua_w, Ua_b, Wq, Uk);

    // K2a: compacted valid-tile work list
    k2a_worklist<<<dim3(1), 256, 0, stream>>>(mask, wl, nchunks);

    // K2: scores (partials) via persistent grid-stride over work list
    k2_scores<<<dim3(1024), 256, 0, stream>>>(Wq, Uk, Va_w, mask, wl, attn, part1, nchunks);

    // K3: sum partials + softmax + exact-zero masking (writes every element of attn)
    k3_softmax<<<dim3(kB * kS), 256, 0, stream>>>(attn, part1, mask, nchunks);

    // K4: contexts (writes every element of ctx, overwriting Uk scratch)
    k4_context<<<dim3(kH / 64, kS / 64, kB), 256, 0, stream>>>(attn, outputs, mask, ctx);
}